// Round 2
// baseline (9555.258 us; speedup 1.0000x reference)
//
#include <hip/hip_runtime.h>
#include <math.h>

#define D_IN 100
#define H    100
#define SEQL 30

// ---------------------------------------------------------------------------
// Kernel 0: Wemb[v, g] = dot(emb[v,:], W_ih[g,:]) + b_ih[g]   (v<V, g<300)
// float4 loads: rows are 400B and 16B-aligned.
// ---------------------------------------------------------------------------
__global__ void k_wemb(const float* __restrict__ emb, const float* __restrict__ W_ih,
                       const float* __restrict__ b_ih, float* __restrict__ Wemb, int total) {
    int t = blockIdx.x * blockDim.x + threadIdx.x;
    if (t >= total) return;
    int v = t / 300, g = t % 300;
    const float4* e = (const float4*)(emb + (long)v * D_IN);
    const float4* w = (const float4*)(W_ih + (long)g * D_IN);
    float acc = 0.f;
#pragma unroll
    for (int d = 0; d < 25; ++d) {
        float4 a = e[d], b = w[d];
        acc += a.x * b.x + a.y * b.y + a.z * b.z + a.w * b.w;
    }
    Wemb[t] = acc + b_ih[g];
}

// ---------------------------------------------------------------------------
// GRU: one thread per node. h[100] lives in VGPRs (constant indices only);
// a persistent LDS image `my[]` (stride 101, conflict-free) serves the ONE
// dynamically-indexed read h[j] and doubles as the hnew buffer. This removes
// the round-1 scratch spill (dynamic h[j] had forced h[] out of registers:
// 750 MB/dispatch spill writes, VALUBusy 26%).
// W_hh/b_hh addresses are wave-uniform -> scalar loads (0 VALU cost).
// Next-j Wemb gather is software-prefetched (grid is only ~0.9 waves/SIMD,
// latency must hide via ILP, not TLP).
// ---------------------------------------------------------------------------
__global__ __launch_bounds__(64, 2) void k_gru(const int* __restrict__ tok,
                                               const float* __restrict__ h0,
                                               const float* __restrict__ Wemb,
                                               const float* __restrict__ W_hh,
                                               const float* __restrict__ b_hh,
                                               float* __restrict__ hout, int n_nodes) {
    __shared__ float hnew[64 * 101];
    int n = blockIdx.x * 64 + threadIdx.x;
    if (n >= n_nodes) return;

    float h[H];
    float* my = hnew + threadIdx.x * 101;
    const float4* h0v = (const float4*)(h0 + (long)n * H);
#pragma unroll
    for (int d = 0; d < 25; ++d) {
        float4 v = h0v[d];
        h[4 * d + 0] = v.x; h[4 * d + 1] = v.y; h[4 * d + 2] = v.z; h[4 * d + 3] = v.w;
        my[4 * d + 0] = v.x; my[4 * d + 1] = v.y; my[4 * d + 2] = v.z; my[4 * d + 3] = v.w;
    }

#pragma unroll 1
    for (int l = 0; l < SEQL; ++l) {
        int t = tok[(long)n * SEQL + l];
        const float* wx = Wemb + (long)t * 300;
        // prefetch j = 0
        float pr = wx[0], pz = wx[100], pn = wx[200];
#pragma unroll 1
        for (int j = 0; j < H; ++j) {
            float wxr = pr, wxz = pz, wxn = pn;
            int jn = (j < 99) ? (j + 1) : 99;     // uniform, branchless
            pr = wx[jn]; pz = wx[100 + jn]; pn = wx[200 + jn];

            const float* Wr = W_hh + j * H;       // uniform -> s_load
            const float* Wz = Wr + 100 * H;
            const float* Wn = Wz + 100 * H;
            float ar = 0.f, az = 0.f, an = 0.f;
#pragma unroll
            for (int d = 0; d < H; ++d) {
                ar = fmaf(Wr[d], h[d], ar);
                az = fmaf(Wz[d], h[d], az);
                an = fmaf(Wn[d], h[d], an);
            }
            float r  = 1.f / (1.f + expf(-(wxr + ar + b_hh[j])));
            float z  = 1.f / (1.f + expf(-(wxz + az + b_hh[100 + j])));
            float nn = tanhf(wxn + r * (an + b_hh[200 + j]));
            float hj = my[j];                     // old h[j] (LDS, dynamic idx OK)
            my[j] = (1.f - z) * nn + z * hj;      // becomes new h[j]
        }
        // copy new h back to registers (constant-index LDS reads)
#pragma unroll
        for (int d = 0; d < H; ++d) h[d] = my[d];
    }
    float4* ho = (float4*)(hout + (long)n * H);
#pragma unroll
    for (int d = 0; d < 25; ++d) {
        float4 v;
        v.x = h[4 * d + 0]; v.y = h[4 * d + 1]; v.z = h[4 * d + 2]; v.w = h[4 * d + 3];
        ho[d] = v;
    }
}

// ---------------------------------------------------------------------------
// Degree (in-edges by dst), then dinv = rsqrt(deg + 1) in-place
// ---------------------------------------------------------------------------
__global__ void k_deg(const int* __restrict__ dst, float* __restrict__ deg, int E) {
    int e = blockIdx.x * blockDim.x + threadIdx.x;
    if (e < E) atomicAdd(&deg[dst[e]], 1.0f);
}

__global__ void k_dinv(float* __restrict__ deg, int N) {
    int n = blockIdx.x * blockDim.x + threadIdx.x;
    if (n < N) deg[n] = rsqrtf(deg[n] + 1.0f);
}

// ---------------------------------------------------------------------------
// xw[n, j] = sum_d x[n, d] * W[d, j]. W staged in LDS (K*100 floats);
// bank pattern (4d + j) % 32 is conflict-free across consecutive j lanes.
// ---------------------------------------------------------------------------
template <int K>
__global__ __launch_bounds__(256) void k_mm(const float* __restrict__ x,
                                            const float* __restrict__ W,
                                            float* __restrict__ out, int total) {
    __shared__ float sW[K * 100];
    for (int i = threadIdx.x; i < K * 100; i += 256) sW[i] = W[i];
    __syncthreads();
    int t = blockIdx.x * blockDim.x + threadIdx.x;
    if (t >= total) return;
    int n = t / 100, j = t % 100;
    const float* xr = x + (long)n * K;
    float acc = 0.f;
#pragma unroll 4
    for (int d = 0; d < K; ++d) acc = fmaf(xr[d], sW[d * 100 + j], acc);
    out[t] = acc;
}

// ---------------------------------------------------------------------------
// Edge aggregation: agg[dst, j] += xw[src, j] * dinv[src] * dinv[dst]
// ---------------------------------------------------------------------------
__global__ void k_agg(const int* __restrict__ src, const int* __restrict__ dst,
                      const float* __restrict__ xw, const float* __restrict__ dinv,
                      float* __restrict__ agg, int total /* E*100 */) {
    int t = blockIdx.x * blockDim.x + threadIdx.x;
    if (t >= total) return;
    int e = t / 100, j = t % 100;
    int s = src[e], d0 = dst[e];
    float c = dinv[s] * dinv[d0];
    atomicAdd(&agg[(long)d0 * 100 + j], xw[(long)s * 100 + j] * c);
}

// ---------------------------------------------------------------------------
// Combine 1: xc1 = agg + xw*dinv^2 + b1 ; xbig = relu([xc1, hn[idx]])
// ---------------------------------------------------------------------------
__global__ void k_comb1(const float* __restrict__ agg, const float* __restrict__ xw,
                        const float* __restrict__ dinv, const float* __restrict__ b1,
                        const float* __restrict__ hn, const int* __restrict__ idx,
                        float* __restrict__ xc1, float* __restrict__ xbig, int total) {
    int t = blockIdx.x * blockDim.x + threadIdx.x;
    if (t >= total) return;
    int n = t / 100, j = t % 100;
    float di = dinv[n];
    float v = agg[t] + xw[t] * di * di + b1[j];
    xc1[t] = v;
    xbig[(long)n * 200 + j] = fmaxf(v, 0.f);
    float rv = hn[(long)idx[n] * 100 + j];
    xbig[(long)n * 200 + 100 + j] = fmaxf(rv, 0.f);
}

// ---------------------------------------------------------------------------
// Output: out = [relu(agg2 + xw2*dinv^2 + b2), xc1[idx]]
// ---------------------------------------------------------------------------
__global__ void k_out(const float* __restrict__ agg, const float* __restrict__ xw,
                      const float* __restrict__ dinv, const float* __restrict__ b2,
                      const float* __restrict__ xc1, const int* __restrict__ idx,
                      float* __restrict__ out, int total) {
    int t = blockIdx.x * blockDim.x + threadIdx.x;
    if (t >= total) return;
    int n = t / 100, j = t % 100;
    float di = dinv[n];
    float v = agg[t] + xw[t] * di * di + b2[j];
    out[(long)n * 200 + j] = fmaxf(v, 0.f);
    out[(long)n * 200 + 100 + j] = xc1[(long)idx[n] * 100 + j];
}

// ---------------------------------------------------------------------------
extern "C" void kernel_launch(void* const* d_in, const int* in_sizes, int n_in,
                              void* d_out, int out_size, void* d_ws, size_t ws_size,
                              hipStream_t stream) {
    const int*   feat    = (const int*)d_in[0];
    const int*   edges   = (const int*)d_in[1];
    const int*   indices = (const int*)d_in[2];
    const float* h0      = (const float*)d_in[3];
    const float* emb     = (const float*)d_in[4];
    const float* W_ih    = (const float*)d_in[5];
    const float* W_hh    = (const float*)d_in[6];
    const float* b_ih    = (const float*)d_in[7];
    const float* b_hh    = (const float*)d_in[8];
    const float* W1      = (const float*)d_in[9];
    const float* b1      = (const float*)d_in[10];
    const float* W2      = (const float*)d_in[11];
    const float* b2      = (const float*)d_in[12];
    float* out = (float*)d_out;

    const int N = in_sizes[2];
    const int E = in_sizes[1] / 2;
    const int V = in_sizes[4] / D_IN;
    const int* src = edges;
    const int* dst = edges + E;

    float* ws   = (float*)d_ws;
    float* hbuf = ws;                         // N*100
    float* Wemb = hbuf + (long)N * H;         // V*300 (reused below)
    float* xwA  = Wemb;                       // reuse: N*100
    float* aggA = Wemb + (long)N * 100;       // reuse: N*100
    float* xc1  = Wemb + (long)V * 300;       // N*100
    float* xbig = xc1 + (long)N * 100;        // N*200
    float* dinv = xbig + (long)N * 200;       // N
    (void)ws_size; (void)n_in; (void)out_size;

    const int B = 256;

    hipMemsetAsync(dinv, 0, (size_t)N * sizeof(float), stream);
    k_deg<<<(E + B - 1) / B, B, 0, stream>>>(dst, dinv, E);

    {
        int total = V * 300;
        k_wemb<<<(total + B - 1) / B, B, 0, stream>>>(emb, W_ih, b_ih, Wemb, total);
    }

    k_gru<<<(N + 63) / 64, 64, 0, stream>>>(feat, h0, Wemb, W_hh, b_hh, hbuf, N);

    k_dinv<<<(N + B - 1) / B, B, 0, stream>>>(dinv, N);

    {
        int total = N * 100;
        k_mm<100><<<(total + B - 1) / B, B, 0, stream>>>(hbuf, W1, xwA, total);
        hipMemsetAsync(aggA, 0, (size_t)total * sizeof(float), stream);
        int etot = E * 100;
        k_agg<<<(etot + B - 1) / B, B, 0, stream>>>(src, dst, xwA, dinv, aggA, etot);
        k_comb1<<<(total + B - 1) / B, B, 0, stream>>>(aggA, xwA, dinv, b1, hbuf, indices,
                                                      xc1, xbig, total);
    }

    {
        int total = N * 100;
        k_mm<200><<<(total + B - 1) / B, B, 0, stream>>>(xbig, W2, xwA, total);
        hipMemsetAsync(aggA, 0, (size_t)total * sizeof(float), stream);
        int etot = E * 100;
        k_agg<<<(etot + B - 1) / B, B, 0, stream>>>(src, dst, xwA, dinv, aggA, etot);
        k_out<<<(total + B - 1) / B, B, 0, stream>>>(aggA, xwA, dinv, b2, xc1, indices,
                                                    out, total);
    }
}

// Round 3
// 6303.735 us; speedup vs baseline: 1.5158x; 1.5158x over previous
//
#include <hip/hip_runtime.h>
#include <math.h>

#define D_IN 100
#define H    100
#define SEQL 30

typedef __attribute__((ext_vector_type(8))) short bf16x8;
typedef __attribute__((ext_vector_type(4))) float f32x4;

__device__ __forceinline__ short f2bf(float f) {
    unsigned u = __builtin_bit_cast(unsigned, f);
    unsigned r = (u + 0x7FFFu + ((u >> 16) & 1u)) >> 16;
    return (short)r;
}
__device__ __forceinline__ float bf2f(short s) {
    unsigned u = ((unsigned)(unsigned short)s) << 16;
    return __builtin_bit_cast(float, u);
}

// ---------------------------------------------------------------------------
// Wemb[v, g] = dot(emb[v,:], W_ih[g,:]) + b_ih[g]   (v<V, g<300)
// ---------------------------------------------------------------------------
__global__ void k_wemb(const float* __restrict__ emb, const float* __restrict__ W_ih,
                       const float* __restrict__ b_ih, float* __restrict__ Wemb, int total) {
    int t = blockIdx.x * blockDim.x + threadIdx.x;
    if (t >= total) return;
    int v = t / 300, g = t % 300;
    const float4* e = (const float4*)(emb + (long)v * D_IN);
    const float4* w = (const float4*)(W_ih + (long)g * D_IN);
    float acc = 0.f;
#pragma unroll
    for (int d = 0; d < 25; ++d) {
        float4 a = e[d], b = w[d];
        acc += a.x * b.x + a.y * b.y + a.z * b.z + a.w * b.w;
    }
    Wemb[t] = acc + b_ih[g];
}

// ---------------------------------------------------------------------------
// Pack W_hh^T into MFMA-B-fragment-major bf16 hi/lo tables.
// B[k][n'] with n' = g*112 + j (each gate padded to 112 cols -> N=336 = 21
// tiles of 16, tiles never straddle gates), k = 0..127 (pad of K=100).
// Element order matches the per-lane frag read:
//   idx = ((nt*4 + ks)*64 + lane)*8 + i,  n' = nt*16 + (lane&15),
//   k = ks*32 + (lane>>4)*8 + i.
// ---------------------------------------------------------------------------
__global__ void k_bpack(const float* __restrict__ W_hh, short* __restrict__ Bhi,
                        short* __restrict__ Blo, int total /* 43008 */) {
    int t = blockIdx.x * blockDim.x + threadIdx.x;
    if (t >= total) return;
    int i    = t & 7;
    int lane = (t >> 3) & 63;
    int blk  = t >> 9;            // nt*4 + ks
    int ks = blk & 3, nt = blk >> 2;
    int np = nt * 16 + (lane & 15);
    int k  = ks * 32 + ((lane >> 4) << 3) + i;
    int g = np / 112, j = np % 112;
    float v = (j < 100 && k < 100) ? W_hh[(g * 100 + j) * 100 + k] : 0.f;
    short hi = f2bf(v);
    short lo = f2bf(v - bf2f(hi));
    Bhi[t] = hi;
    Blo[t] = lo;
}

// ---------------------------------------------------------------------------
// MFMA GRU: one wave per 16 nodes, persistent over all 30 steps.
// h kept in LDS as bf16 hi+lo (exact to 2^-17); per step:
//   gh[16 x 336] = h[16 x 128] @ B  via mfma_f32_16x16x32_bf16, split-product
//   (Ahi*Bhi + Ahi*Blo + Alo*Bhi) for fp32-grade precision.
// A-layout (verified): lane holds A[m=lane&15][k=(lane>>4)*8 + i]
// B-layout (mirror):   lane holds B[k=(lane>>4)*8 + i][n=lane&15]
// C/D layout (verified): col = lane&15, row = (lane>>4)*4 + reg
// Gate g of column j lands in acc tile nt = g*7 + jt at the SAME (lane,reg)
// for all three gates -> epilogue is pointwise. Wemb gather (wx, already
// includes b_ih) double-buffered one j-tile ahead.
// Single-wave block: no __syncthreads in the hot loop needed.
// ---------------------------------------------------------------------------
__global__ __launch_bounds__(64) void k_gru_mfma(
        const int* __restrict__ tok, const float* __restrict__ h0,
        const float* __restrict__ Wemb, const short* __restrict__ Bhi,
        const short* __restrict__ Blo, const float* __restrict__ b_hh,
        float* __restrict__ hout, int n_nodes) {
    // node stride 136 shorts = 272 B (17*16: keeps b128 reads aligned, ~2-way banks)
    __shared__ short hA0[16 * 136];
    __shared__ short hA1[16 * 136];

    const int lane  = threadIdx.x;
    const int node0 = blockIdx.x * 16;
    const int n0 = lane & 15;          // A-row / D-col / j-within-tile
    const int q  = lane >> 4;

    // ---- init h (split h0 into hi/lo, zero-pad k=100..127) ----
    for (int i = lane; i < 16 * 128; i += 64) {
        int nd = i >> 7, c = i & 127;
        float v = (c < 100) ? h0[(long)(node0 + nd) * 100 + c] : 0.f;
        short hi = f2bf(v);
        hA0[nd * 136 + c] = hi;
        hA1[nd * 136 + c] = f2bf(v - bf2f(hi));
    }
    __syncthreads();

#pragma unroll 1
    for (int l = 0; l < SEQL; ++l) {
        // tokens for the 4 nodes this lane handles in the epilogue (m = 4q+r)
        int t0 = tok[(long)(node0 + 4 * q + 0) * SEQL + l];
        int t1 = tok[(long)(node0 + 4 * q + 1) * SEQL + l];
        int t2 = tok[(long)(node0 + 4 * q + 2) * SEQL + l];
        int t3 = tok[(long)(node0 + 4 * q + 3) * SEQL + l];
        long tb[4] = {(long)t0 * 300, (long)t1 * 300, (long)t2 * 300, (long)t3 * 300};

        // A-fragments for this step (4 k-steps, hi & lo)
        bf16x8 aHi[4], aLo[4];
#pragma unroll
        for (int ks = 0; ks < 4; ++ks) {
            int off = n0 * 136 + ks * 32 + q * 8;
            aHi[ks] = *(const bf16x8*)&hA0[off];
            aLo[ks] = *(const bf16x8*)&hA1[off];
        }

        // gather wx for jt=0
        float wxc[12], wxn[12];
#pragma unroll
        for (int g = 0; g < 3; ++g)
#pragma unroll
            for (int r = 0; r < 4; ++r)
                wxc[g * 4 + r] = Wemb[tb[r] + g * 100 + n0];

#pragma unroll
        for (int jt = 0; jt < 7; ++jt) {
            f32x4 acc[3];
#pragma unroll
            for (int g = 0; g < 3; ++g) acc[g] = (f32x4){0.f, 0.f, 0.f, 0.f};

#pragma unroll
            for (int g = 0; g < 3; ++g) {
                int nt = g * 7 + jt;
#pragma unroll
                for (int ks = 0; ks < 4; ++ks) {
                    long bo = ((long)(nt * 4 + ks) * 64 + lane) * 8;
                    bf16x8 bh = *(const bf16x8*)&Bhi[bo];
                    bf16x8 bl = *(const bf16x8*)&Blo[bo];
                    acc[g] = __builtin_amdgcn_mfma_f32_16x16x32_bf16(aHi[ks], bh, acc[g], 0, 0, 0);
                    acc[g] = __builtin_amdgcn_mfma_f32_16x16x32_bf16(aHi[ks], bl, acc[g], 0, 0, 0);
                    acc[g] = __builtin_amdgcn_mfma_f32_16x16x32_bf16(aLo[ks], bh, acc[g], 0, 0, 0);
                }
            }

            // prefetch next j-tile's wx
            if (jt < 6) {
                int j2 = 16 * (jt + 1) + n0;
                int jc2 = j2 < 100 ? j2 : 99;
#pragma unroll
                for (int g = 0; g < 3; ++g)
#pragma unroll
                    for (int r = 0; r < 4; ++r)
                        wxn[g * 4 + r] = Wemb[tb[r] + g * 100 + jc2];
            }

            // ---- epilogue: gates + h update ----
            int j  = 16 * jt + n0;
            int jc = j < 100 ? j : 99;
            float bhr = b_hh[jc], bhz = b_hh[100 + jc], bhn = b_hh[200 + jc];
#pragma unroll
            for (int r = 0; r < 4; ++r) {
                int m   = 4 * q + r;
                int off = m * 136 + jc;
                float hold = bf2f(hA0[off]) + bf2f(hA1[off]);
                float pr = wxc[r]     + acc[0][r] + bhr;
                float pz = wxc[4 + r] + acc[1][r] + bhz;
                float rr = __builtin_amdgcn_rcpf(1.f + __expf(-pr));
                float zz = __builtin_amdgcn_rcpf(1.f + __expf(-pz));
                float pn = wxc[8 + r] + rr * (acc[2][r] + bhn);
                float th = 1.f - 2.f * __builtin_amdgcn_rcpf(1.f + __expf(2.f * pn));
                float hnew = (1.f - zz) * th + zz * hold;
                if (j < 100) {
                    short hi = f2bf(hnew);
                    hA0[off] = hi;
                    hA1[off] = f2bf(hnew - bf2f(hi));
                }
            }
#pragma unroll
            for (int i = 0; i < 12; ++i) wxc[i] = wxn[i];
        }
        __syncthreads();   // single wave: ~free; pins LDS ordering across steps
    }

    // ---- write hn (fp32) ----
    for (int i = lane; i < 16 * 100; i += 64) {
        int nd = i / 100, c = i % 100;
        int off = nd * 136 + c;
        hout[(long)(node0 + nd) * 100 + c] = bf2f(hA0[off]) + bf2f(hA1[off]);
    }
}

// ---------------------------------------------------------------------------
// Degree, dinv
// ---------------------------------------------------------------------------
__global__ void k_deg(const int* __restrict__ dst, float* __restrict__ deg, int E) {
    int e = blockIdx.x * blockDim.x + threadIdx.x;
    if (e < E) atomicAdd(&deg[dst[e]], 1.0f);
}

__global__ void k_dinv(float* __restrict__ deg, int N) {
    int n = blockIdx.x * blockDim.x + threadIdx.x;
    if (n < N) deg[n] = rsqrtf(deg[n] + 1.0f);
}

// ---------------------------------------------------------------------------
// xw[n, j] = sum_d x[n, d] * W[d, j], W staged in LDS
// ---------------------------------------------------------------------------
template <int K>
__global__ __launch_bounds__(256) void k_mm(const float* __restrict__ x,
                                            const float* __restrict__ W,
                                            float* __restrict__ out, int total) {
    __shared__ float sW[K * 100];
    for (int i = threadIdx.x; i < K * 100; i += 256) sW[i] = W[i];
    __syncthreads();
    int t = blockIdx.x * blockDim.x + threadIdx.x;
    if (t >= total) return;
    int n = t / 100, j = t % 100;
    const float* xr = x + (long)n * K;
    float acc = 0.f;
#pragma unroll 4
    for (int d = 0; d < K; ++d) acc = fmaf(xr[d], sW[d * 100 + j], acc);
    out[t] = acc;
}

// ---------------------------------------------------------------------------
// Edge aggregation via atomics
// ---------------------------------------------------------------------------
__global__ void k_agg(const int* __restrict__ src, const int* __restrict__ dst,
                      const float* __restrict__ xw, const float* __restrict__ dinv,
                      float* __restrict__ agg, int total /* E*100 */) {
    int t = blockIdx.x * blockDim.x + threadIdx.x;
    if (t >= total) return;
    int e = t / 100, j = t % 100;
    int s = src[e], d0 = dst[e];
    float c = dinv[s] * dinv[d0];
    atomicAdd(&agg[(long)d0 * 100 + j], xw[(long)s * 100 + j] * c);
}

// ---------------------------------------------------------------------------
// Combine 1: xc1 = agg + xw*dinv^2 + b1 ; xbig = relu([xc1, hn[idx]])
// ---------------------------------------------------------------------------
__global__ void k_comb1(const float* __restrict__ agg, const float* __restrict__ xw,
                        const float* __restrict__ dinv, const float* __restrict__ b1,
                        const float* __restrict__ hn, const int* __restrict__ idx,
                        float* __restrict__ xc1, float* __restrict__ xbig, int total) {
    int t = blockIdx.x * blockDim.x + threadIdx.x;
    if (t >= total) return;
    int n = t / 100, j = t % 100;
    float di = dinv[n];
    float v = agg[t] + xw[t] * di * di + b1[j];
    xc1[t] = v;
    xbig[(long)n * 200 + j] = fmaxf(v, 0.f);
    float rv = hn[(long)idx[n] * 100 + j];
    xbig[(long)n * 200 + 100 + j] = fmaxf(rv, 0.f);
}

// ---------------------------------------------------------------------------
// Output: out = [relu(agg2 + xw2*dinv^2 + b2), xc1[idx]]
// ---------------------------------------------------------------------------
__global__ void k_out(const float* __restrict__ agg, const float* __restrict__ xw,
                      const float* __restrict__ dinv, const float* __restrict__ b2,
                      const float* __restrict__ xc1, const int* __restrict__ idx,
                      float* __restrict__ out, int total) {
    int t = blockIdx.x * blockDim.x + threadIdx.x;
    if (t >= total) return;
    int n = t / 100, j = t % 100;
    float di = dinv[n];
    float v = agg[t] + xw[t] * di * di + b2[j];
    out[(long)n * 200 + j] = fmaxf(v, 0.f);
    out[(long)n * 200 + 100 + j] = xc1[(long)idx[n] * 100 + j];
}

// ---------------------------------------------------------------------------
extern "C" void kernel_launch(void* const* d_in, const int* in_sizes, int n_in,
                              void* d_out, int out_size, void* d_ws, size_t ws_size,
                              hipStream_t stream) {
    const int*   feat    = (const int*)d_in[0];
    const int*   edges   = (const int*)d_in[1];
    const int*   indices = (const int*)d_in[2];
    const float* h0      = (const float*)d_in[3];
    const float* emb     = (const float*)d_in[4];
    const float* W_ih    = (const float*)d_in[5];
    const float* W_hh    = (const float*)d_in[6];
    const float* b_ih    = (const float*)d_in[7];
    const float* b_hh    = (const float*)d_in[8];
    const float* W1      = (const float*)d_in[9];
    const float* b1      = (const float*)d_in[10];
    const float* W2      = (const float*)d_in[11];
    const float* b2      = (const float*)d_in[12];
    float* out = (float*)d_out;

    const int N = in_sizes[2];
    const int E = in_sizes[1] / 2;
    const int V = in_sizes[4] / D_IN;
    const int* src = edges;
    const int* dst = edges + E;

    float* ws   = (float*)d_ws;
    float* hbuf = ws;                         // N*100
    float* Wemb = hbuf + (long)N * H;         // V*300 (reused below)
    float* xwA  = Wemb;                       // reuse: N*100
    float* aggA = Wemb + (long)N * 100;       // reuse: N*100
    float* xc1  = Wemb + (long)V * 300;       // N*100
    float* xbig = xc1 + (long)N * 100;        // N*200
    float* dinv = xbig + (long)N * 200;       // N
    short* Bhi  = (short*)(dinv + N);         // 43008 bf16 (16B-aligned)
    short* Blo  = Bhi + 43008;                // 43008 bf16
    (void)ws_size; (void)n_in; (void)out_size;

    const int B = 256;

    hipMemsetAsync(dinv, 0, (size_t)N * sizeof(float), stream);
    k_deg<<<(E + B - 1) / B, B, 0, stream>>>(dst, dinv, E);

    k_bpack<<<(43008 + B - 1) / B, B, 0, stream>>>(W_hh, Bhi, Blo, 43008);

    {
        int total = V * 300;
        k_wemb<<<(total + B - 1) / B, B, 0, stream>>>(emb, W_ih, b_ih, Wemb, total);
    }

    k_gru_mfma<<<(N + 15) / 16, 64, 0, stream>>>(feat, h0, Wemb, Bhi, Blo, b_hh, hbuf, N);

    k_dinv<<<(N + B - 1) / B, B, 0, stream>>>(dinv, N);

    {
        int total = N * 100;
        k_mm<100><<<(total + B - 1) / B, B, 0, stream>>>(hbuf, W1, xwA, total);
        hipMemsetAsync(aggA, 0, (size_t)total * sizeof(float), stream);
        int etot = E * 100;
        k_agg<<<(etot + B - 1) / B, B, 0, stream>>>(src, dst, xwA, dinv, aggA, etot);
        k_comb1<<<(total + B - 1) / B, B, 0, stream>>>(aggA, xwA, dinv, b1, hbuf, indices,
                                                      xc1, xbig, total);
    }

    {
        int total = N * 100;
        k_mm<200><<<(total + B - 1) / B, B, 0, stream>>>(xbig, W2, xwA, total);
        hipMemsetAsync(aggA, 0, (size_t)total * sizeof(float), stream);
        int etot = E * 100;
        k_agg<<<(etot + B - 1) / B, B, 0, stream>>>(src, dst, xwA, dinv, aggA, etot);
        k_out<<<(total + B - 1) / B, B, 0, stream>>>(aggA, xwA, dinv, b2, xc1, indices,
                                                    out, total);
    }
}

// Round 4
// 1997.653 us; speedup vs baseline: 4.7832x; 3.1556x over previous
//
#include <hip/hip_runtime.h>
#include <math.h>

#define D_IN 100
#define H    100
#define SEQL 30

typedef __attribute__((ext_vector_type(8))) short bf16x8;
typedef __attribute__((ext_vector_type(4))) float f32x4;

__device__ __forceinline__ short f2bf(float f) {
    unsigned u = __builtin_bit_cast(unsigned, f);
    unsigned r = (u + 0x7FFFu + ((u >> 16) & 1u)) >> 16;
    return (short)r;
}
__device__ __forceinline__ float bf2f(short s) {
    unsigned u = ((unsigned)(unsigned short)s) << 16;
    return __builtin_bit_cast(float, u);
}

// ---------------------------------------------------------------------------
// Wemb = emb @ W_ih^T + b_ih, LDS-tiled. W_ih transposed into LDS once per
// block (sWT[d][g], conflict-free b32 reads: consecutive g lanes -> consecutive
// banks). 64 emb rows per block, 512 threads (8 waves -> decent hiding at
// 1 block/CU forced by the 120KB LDS tile).
// ---------------------------------------------------------------------------
__global__ __launch_bounds__(512) void k_wemb_t(const float* __restrict__ emb,
                                                const float* __restrict__ W_ih,
                                                const float* __restrict__ b_ih,
                                                float* __restrict__ Wemb, int V) {
    __shared__ float sWT[100 * 300];   // [d][g], 120KB
    __shared__ float sb[300];
    for (int i = threadIdx.x; i < 30000; i += 512) {
        int g = i / 100, d = i % 100;      // global-coalesced read
        sWT[d * 300 + g] = W_ih[i];
    }
    for (int i = threadIdx.x; i < 300; i += 512) sb[i] = b_ih[i];
    __syncthreads();

    int v0 = blockIdx.x * 64;
    for (int t = threadIdx.x; t < 64 * 300; t += 512) {
        int vl = t / 300, g = t % 300;
        int v = v0 + vl;
        if (v >= V) continue;
        const float4* e = (const float4*)(emb + (long)v * 100);
        float acc = 0.f;
#pragma unroll
        for (int d4 = 0; d4 < 25; ++d4) {
            float4 ev = e[d4];
            acc = fmaf(ev.x, sWT[(4 * d4 + 0) * 300 + g], acc);
            acc = fmaf(ev.y, sWT[(4 * d4 + 1) * 300 + g], acc);
            acc = fmaf(ev.z, sWT[(4 * d4 + 2) * 300 + g], acc);
            acc = fmaf(ev.w, sWT[(4 * d4 + 3) * 300 + g], acc);
        }
        Wemb[(long)v * 300 + g] = acc + sb[g];
    }
}

// ---------------------------------------------------------------------------
// Pack W_hh^T into MFMA-B-fragment-major bf16 hi/lo tables (unchanged from
// round 3 -- layout verified by a passing run).
//   idx = ((nt*4 + ks)*64 + lane)*8 + i,  n' = nt*16 + (lane&15),
//   k = ks*32 + (lane>>4)*8 + i,  n' = g*112 + j.
// ---------------------------------------------------------------------------
__global__ void k_bpack(const float* __restrict__ W_hh, short* __restrict__ Bhi,
                        short* __restrict__ Blo, int total /* 43008 */) {
    int t = blockIdx.x * blockDim.x + threadIdx.x;
    if (t >= total) return;
    int i    = t & 7;
    int lane = (t >> 3) & 63;
    int blk  = t >> 9;            // nt*4 + ks
    int ks = blk & 3, nt = blk >> 2;
    int np = nt * 16 + (lane & 15);
    int k  = ks * 32 + ((lane >> 4) << 3) + i;
    int g = np / 112, j = np % 112;
    float v = (j < 100 && k < 100) ? W_hh[(g * 100 + j) * 100 + k] : 0.f;
    short hi = f2bf(v);
    short lo = f2bf(v - bf2f(hi));
    Bhi[t] = hi;
    Blo[t] = lo;
}

// ---------------------------------------------------------------------------
// MFMA GRU, 7 waves/block, 16 nodes/block. Wave w owns column-tile jt=w for
// ALL 3 gates (B tiles {w, 7+w, 14+w}): 24 bf16x8 B-frags = 96 VGPR, loaded
// ONCE -> zero B traffic in the 30-step loop (round-3 bottleneck: 19 GB of
// L2 B-frag streaming, MfmaUtil 4.3%). Epilogue is wave-local (all gates of
// column j in this wave); h exchanged across waves via LDS hi/lo tables,
// 2 barriers/step. h_old carried in registers (the lane that computes column
// j is the lane that wrote it last step). Token + Wemb gathers pipelined one
// step ahead; latency hides behind MFMA.
// ---------------------------------------------------------------------------
__global__ __launch_bounds__(448, 2) void k_gru_mfma(
        const int* __restrict__ tok, const float* __restrict__ h0,
        const float* __restrict__ Wemb, const short* __restrict__ Bhi,
        const short* __restrict__ Blo, const float* __restrict__ b_hh,
        float* __restrict__ hout, int n_nodes) {
    __shared__ short hA0[16 * 136];   // h hi, [node][k], stride 136 shorts
    __shared__ short hA1[16 * 136];   // h lo

    const int tid  = threadIdx.x;
    const int w    = tid >> 6;        // wave id 0..6 = column tile
    const int lane = tid & 63;
    const int n0   = lane & 15;
    const int q    = lane >> 4;
    const int node0 = blockIdx.x * 16;

    // ---- B fragments: 3 gates x 4 k-steps, hi+lo, loaded once ----
    bf16x8 bh[3][4], bl[3][4];
#pragma unroll
    for (int g = 0; g < 3; ++g)
#pragma unroll
        for (int ks = 0; ks < 4; ++ks) {
            long bo = ((long)((g * 7 + w) * 4 + ks) * 64 + lane) * 8;
            bh[g][ks] = *(const bf16x8*)&Bhi[bo];
            bl[g][ks] = *(const bf16x8*)&Blo[bo];
        }

    // ---- init h tables (split h0 into hi/lo, zero-pad k=100..127) ----
    for (int i = tid; i < 16 * 128; i += 448) {
        int nd = i >> 7, c = i & 127;
        int row = node0 + nd; if (row >= n_nodes) row = n_nodes - 1;
        float v = (c < 100) ? h0[(long)row * 100 + c] : 0.f;
        short hi = f2bf(v);
        hA0[nd * 136 + c] = hi;
        hA1[nd * 136 + c] = f2bf(v - bf2f(hi));
    }

    // ---- per-lane constants ----
    const int j   = 16 * w + n0;          // output column this lane owns
    const int jc  = j < 100 ? j : 99;
    const bool jok = (j < 100);
    const float bhr = b_hh[jc], bhz = b_hh[100 + jc], bhn = b_hh[200 + jc];

    int rows[4];
#pragma unroll
    for (int r = 0; r < 4; ++r) {
        int row = node0 + 4 * q + r;
        rows[r] = row < n_nodes ? row : n_nodes - 1;
    }

    // h_old for this lane's 4 (node, j) cells, register-resident
    float hprev[4];
#pragma unroll
    for (int r = 0; r < 4; ++r) hprev[r] = h0[(long)rows[r] * 100 + jc];

    __syncthreads();

    // ---- prefetch step 0 tokens + wx ----
    long tb[4];
#pragma unroll
    for (int r = 0; r < 4; ++r) tb[r] = (long)tok[(long)rows[r] * SEQL] * 300;
    float wxc[12];
#pragma unroll
    for (int g = 0; g < 3; ++g)
#pragma unroll
        for (int r = 0; r < 4; ++r) wxc[g * 4 + r] = Wemb[tb[r] + g * 100 + jc];

#pragma unroll 1
    for (int l = 0; l < SEQL; ++l) {
        // A-fragments (all waves read the same values -- LDS broadcast)
        bf16x8 aHi[4], aLo[4];
#pragma unroll
        for (int ks = 0; ks < 4; ++ks) {
            int off = n0 * 136 + ks * 32 + q * 8;
            aHi[ks] = *(const bf16x8*)&hA0[off];
            aLo[ks] = *(const bf16x8*)&hA1[off];
        }
        // prefetch next step's tokens (independent of LDS)
        long tbn[4];
        if (l < SEQL - 1) {
#pragma unroll
            for (int r = 0; r < 4; ++r)
                tbn[r] = (long)tok[(long)rows[r] * SEQL + l + 1] * 300;
        }
        __syncthreads();   // all A reads done -> safe to write hA later

        f32x4 acc[3];
#pragma unroll
        for (int g = 0; g < 3; ++g) acc[g] = (f32x4){0.f, 0.f, 0.f, 0.f};
#pragma unroll
        for (int g = 0; g < 3; ++g)
#pragma unroll
            for (int ks = 0; ks < 4; ++ks) {
                acc[g] = __builtin_amdgcn_mfma_f32_16x16x32_bf16(aHi[ks], bh[g][ks], acc[g], 0, 0, 0);
                acc[g] = __builtin_amdgcn_mfma_f32_16x16x32_bf16(aHi[ks], bl[g][ks], acc[g], 0, 0, 0);
                acc[g] = __builtin_amdgcn_mfma_f32_16x16x32_bf16(aLo[ks], bh[g][ks], acc[g], 0, 0, 0);
            }

        // prefetch next step's wx (hides L2/L3 latency behind epilogue+barrier)
        float wxn[12];
        if (l < SEQL - 1) {
#pragma unroll
            for (int g = 0; g < 3; ++g)
#pragma unroll
                for (int r = 0; r < 4; ++r)
                    wxn[g * 4 + r] = Wemb[tbn[r] + g * 100 + jc];
        }

        // ---- epilogue: gates + h update (wave-local) ----
#pragma unroll
        for (int r = 0; r < 4; ++r) {
            float pr = wxc[r]     + acc[0][r] + bhr;
            float pz = wxc[4 + r] + acc[1][r] + bhz;
            float rr = __builtin_amdgcn_rcpf(1.f + __expf(-pr));
            float zz = __builtin_amdgcn_rcpf(1.f + __expf(-pz));
            float pn = wxc[8 + r] + rr * (acc[2][r] + bhn);
            float th = 1.f - 2.f * __builtin_amdgcn_rcpf(1.f + __expf(2.f * pn));
            float hnew = (1.f - zz) * th + zz * hprev[r];
            hprev[r] = hnew;
            if (jok) {
                int off = (4 * q + r) * 136 + j;
                short hi = f2bf(hnew);
                hA0[off] = hi;
                hA1[off] = f2bf(hnew - bf2f(hi));
            }
        }
        if (l < SEQL - 1) {
#pragma unroll
            for (int i = 0; i < 12; ++i) wxc[i] = wxn[i];
#pragma unroll
            for (int r = 0; r < 4; ++r) tb[r] = tbn[r];
        }
        __syncthreads();   // h writes visible before next step's A reads
    }

    // ---- write hn (fp32) ----
    for (int i = tid; i < 16 * 100; i += 448) {
        int nd = i / 100, c = i % 100;
        if (node0 + nd < n_nodes)
            hout[(long)(node0 + nd) * 100 + c] = bf2f(hA0[nd * 136 + c]) + bf2f(hA1[nd * 136 + c]);
    }
}

// ---------------------------------------------------------------------------
// Degree, dinv
// ---------------------------------------------------------------------------
__global__ void k_deg(const int* __restrict__ dst, float* __restrict__ deg, int E) {
    int e = blockIdx.x * blockDim.x + threadIdx.x;
    if (e < E) atomicAdd(&deg[dst[e]], 1.0f);
}

__global__ void k_dinv(float* __restrict__ deg, int N) {
    int n = blockIdx.x * blockDim.x + threadIdx.x;
    if (n < N) deg[n] = rsqrtf(deg[n] + 1.0f);
}

// ---------------------------------------------------------------------------
// xw[n, j] = sum_d x[n, d] * W[d, j], W staged in LDS
// ---------------------------------------------------------------------------
template <int K>
__global__ __launch_bounds__(256) void k_mm(const float* __restrict__ x,
                                            const float* __restrict__ W,
                                            float* __restrict__ out, int total) {
    __shared__ float sW[K * 100];
    for (int i = threadIdx.x; i < K * 100; i += 256) sW[i] = W[i];
    __syncthreads();
    int t = blockIdx.x * blockDim.x + threadIdx.x;
    if (t >= total) return;
    int n = t / 100, j = t % 100;
    const float* xr = x + (long)n * K;
    float acc = 0.f;
#pragma unroll 4
    for (int d = 0; d < K; ++d) acc = fmaf(xr[d], sW[d * 100 + j], acc);
    out[t] = acc;
}

// ---------------------------------------------------------------------------
// Edge aggregation via atomics
// ---------------------------------------------------------------------------
__global__ void k_agg(const int* __restrict__ src, const int* __restrict__ dst,
                      const float* __restrict__ xw, const float* __restrict__ dinv,
                      float* __restrict__ agg, int total /* E*100 */) {
    int t = blockIdx.x * blockDim.x + threadIdx.x;
    if (t >= total) return;
    int e = t / 100, j = t % 100;
    int s = src[e], d0 = dst[e];
    float c = dinv[s] * dinv[d0];
    atomicAdd(&agg[(long)d0 * 100 + j], xw[(long)s * 100 + j] * c);
}

// ---------------------------------------------------------------------------
// Combine 1: xc1 = agg + xw*dinv^2 + b1 ; xbig = relu([xc1, hn[idx]])
// ---------------------------------------------------------------------------
__global__ void k_comb1(const float* __restrict__ agg, const float* __restrict__ xw,
                        const float* __restrict__ dinv, const float* __restrict__ b1,
                        const float* __restrict__ hn, const int* __restrict__ idx,
                        float* __restrict__ xc1, float* __restrict__ xbig, int total) {
    int t = blockIdx.x * blockDim.x + threadIdx.x;
    if (t >= total) return;
    int n = t / 100, j = t % 100;
    float di = dinv[n];
    float v = agg[t] + xw[t] * di * di + b1[j];
    xc1[t] = v;
    xbig[(long)n * 200 + j] = fmaxf(v, 0.f);
    float rv = hn[(long)idx[n] * 100 + j];
    xbig[(long)n * 200 + 100 + j] = fmaxf(rv, 0.f);
}

// ---------------------------------------------------------------------------
// Output: out = [relu(agg2 + xw2*dinv^2 + b2), xc1[idx]]
// ---------------------------------------------------------------------------
__global__ void k_out(const float* __restrict__ agg, const float* __restrict__ xw,
                      const float* __restrict__ dinv, const float* __restrict__ b2,
                      const float* __restrict__ xc1, const int* __restrict__ idx,
                      float* __restrict__ out, int total) {
    int t = blockIdx.x * blockDim.x + threadIdx.x;
    if (t >= total) return;
    int n = t / 100, j = t % 100;
    float di = dinv[n];
    float v = agg[t] + xw[t] * di * di + b2[j];
    out[(long)n * 200 + j] = fmaxf(v, 0.f);
    out[(long)n * 200 + 100 + j] = xc1[(long)idx[n] * 100 + j];
}

// ---------------------------------------------------------------------------
extern "C" void kernel_launch(void* const* d_in, const int* in_sizes, int n_in,
                              void* d_out, int out_size, void* d_ws, size_t ws_size,
                              hipStream_t stream) {
    const int*   feat    = (const int*)d_in[0];
    const int*   edges   = (const int*)d_in[1];
    const int*   indices = (const int*)d_in[2];
    const float* h0      = (const float*)d_in[3];
    const float* emb     = (const float*)d_in[4];
    const float* W_ih    = (const float*)d_in[5];
    const float* W_hh    = (const float*)d_in[6];
    const float* b_ih    = (const float*)d_in[7];
    const float* b_hh    = (const float*)d_in[8];
    const float* W1      = (const float*)d_in[9];
    const float* b1      = (const float*)d_in[10];
    const float* W2      = (const float*)d_in[11];
    const float* b2      = (const float*)d_in[12];
    float* out = (float*)d_out;

    const int N = in_sizes[2];
    const int E = in_sizes[1] / 2;
    const int V = in_sizes[4] / D_IN;
    const int* src = edges;
    const int* dst = edges + E;

    float* ws   = (float*)d_ws;
    float* hbuf = ws;                         // N*100
    float* Wemb = hbuf + (long)N * H;         // V*300 (reused below)
    float* xwA  = Wemb;                       // reuse: N*100
    float* aggA = Wemb + (long)N * 100;       // reuse: N*100
    float* xc1  = Wemb + (long)V * 300;       // N*100
    float* xbig = xc1 + (long)N * 100;        // N*200
    float* dinv = xbig + (long)N * 200;       // N
    short* Bhi  = (short*)(dinv + N);         // 43008 bf16
    short* Blo  = Bhi + 43008;                // 43008 bf16
    (void)ws_size; (void)n_in; (void)out_size;

    const int B = 256;

    hipMemsetAsync(dinv, 0, (size_t)N * sizeof(float), stream);
    k_deg<<<(E + B - 1) / B, B, 0, stream>>>(dst, dinv, E);

    k_bpack<<<(43008 + B - 1) / B, B, 0, stream>>>(W_hh, Bhi, Blo, 43008);

    k_wemb_t<<<(V + 63) / 64, 512, 0, stream>>>(emb, W_ih, b_ih, Wemb, V);

    k_gru_mfma<<<(N + 15) / 16, 448, 0, stream>>>(feat, h0, Wemb, Bhi, Blo, b_hh, hbuf, N);

    k_dinv<<<(N + B - 1) / B, B, 0, stream>>>(dinv, N);

    {
        int total = N * 100;
        k_mm<100><<<(total + B - 1) / B, B, 0, stream>>>(hbuf, W1, xwA, total);
        hipMemsetAsync(aggA, 0, (size_t)total * sizeof(float), stream);
        int etot = E * 100;
        k_agg<<<(etot + B - 1) / B, B, 0, stream>>>(src, dst, xwA, dinv, aggA, etot);
        k_comb1<<<(total + B - 1) / B, B, 0, stream>>>(aggA, xwA, dinv, b1, hbuf, indices,
                                                      xc1, xbig, total);
    }

    {
        int total = N * 100;
        k_mm<200><<<(total + B - 1) / B, B, 0, stream>>>(xbig, W2, xwA, total);
        hipMemsetAsync(aggA, 0, (size_t)total * sizeof(float), stream);
        int etot = E * 100;
        k_agg<<<(etot + B - 1) / B, B, 0, stream>>>(src, dst, xwA, dinv, aggA, etot);
        k_out<<<(total + B - 1) / B, B, 0, stream>>>(aggA, xwA, dinv, b2, xc1, indices,
                                                    out, total);
    }
}

// Round 5
// 1372.310 us; speedup vs baseline: 6.9629x; 1.4557x over previous
//
#include <hip/hip_runtime.h>
#include <math.h>

#define D_IN 100
#define H    100
#define SEQL 30

typedef __attribute__((ext_vector_type(8))) short bf16x8;
typedef __attribute__((ext_vector_type(4))) float f32x4;

__device__ __forceinline__ short f2bf(float f) {
    unsigned u = __builtin_bit_cast(unsigned, f);
    unsigned r = (u + 0x7FFFu + ((u >> 16) & 1u)) >> 16;
    return (short)r;
}
__device__ __forceinline__ float bf2f(short s) {
    unsigned u = ((unsigned)(unsigned short)s) << 16;
    return __builtin_bit_cast(float, u);
}

// ---------------------------------------------------------------------------
// Wemb = emb @ W_ih^T + b_ih. W_ih transposed into LDS; each thread produces
// a float4 of 4 consecutive g columns -> b128 LDS reads (4x fewer LDS instrs
// than the round-4 b32 version).
// ---------------------------------------------------------------------------
__global__ __launch_bounds__(512) void k_wemb_t(const float* __restrict__ emb,
                                                const float* __restrict__ W_ih,
                                                const float* __restrict__ b_ih,
                                                float* __restrict__ Wemb, int V) {
    __shared__ float sWT[100 * 300];   // [d][g], 120KB
    __shared__ float sb[300];
    for (int i = threadIdx.x; i < 30000; i += 512) {
        int g = i / 100, d = i % 100;
        sWT[d * 300 + g] = W_ih[i];
    }
    for (int i = threadIdx.x; i < 300; i += 512) sb[i] = b_ih[i];
    __syncthreads();

    int v0 = blockIdx.x * 64;
    for (int t = threadIdx.x; t < 64 * 75; t += 512) {
        int vl = t / 75, gq = t % 75;
        int v = v0 + vl;
        if (v >= V) continue;
        const float4* e = (const float4*)(emb + (long)v * 100);
        float4 acc = *(const float4*)&sb[4 * gq];
#pragma unroll
        for (int d4 = 0; d4 < 25; ++d4) {
            float4 ev = e[d4];
            float4 w0 = *(const float4*)&sWT[(4 * d4 + 0) * 300 + 4 * gq];
            float4 w1 = *(const float4*)&sWT[(4 * d4 + 1) * 300 + 4 * gq];
            float4 w2 = *(const float4*)&sWT[(4 * d4 + 2) * 300 + 4 * gq];
            float4 w3 = *(const float4*)&sWT[(4 * d4 + 3) * 300 + 4 * gq];
            acc.x = fmaf(ev.x, w0.x, fmaf(ev.y, w1.x, fmaf(ev.z, w2.x, fmaf(ev.w, w3.x, acc.x))));
            acc.y = fmaf(ev.x, w0.y, fmaf(ev.y, w1.y, fmaf(ev.z, w2.y, fmaf(ev.w, w3.y, acc.y))));
            acc.z = fmaf(ev.x, w0.z, fmaf(ev.y, w1.z, fmaf(ev.z, w2.z, fmaf(ev.w, w3.z, acc.z))));
            acc.w = fmaf(ev.x, w0.w, fmaf(ev.y, w1.w, fmaf(ev.z, w2.w, fmaf(ev.w, w3.w, acc.w))));
        }
        *(float4*)(Wemb + (long)v * 300 + 4 * gq) = acc;
    }
}

// ---------------------------------------------------------------------------
// Pack W_hh^T into MFMA-B-fragment-major bf16 hi/lo tables (layout verified).
// ---------------------------------------------------------------------------
__global__ void k_bpack(const float* __restrict__ W_hh, short* __restrict__ Bhi,
                        short* __restrict__ Blo, int total /* 43008 */) {
    int t = blockIdx.x * blockDim.x + threadIdx.x;
    if (t >= total) return;
    int i    = t & 7;
    int lane = (t >> 3) & 63;
    int blk  = t >> 9;            // nt*4 + ks
    int ks = blk & 3, nt = blk >> 2;
    int np = nt * 16 + (lane & 15);
    int k  = ks * 32 + ((lane >> 4) << 3) + i;
    int g = np / 112, j = np % 112;
    float v = (j < 100 && k < 100) ? W_hh[(g * 100 + j) * 100 + k] : 0.f;
    short hi = f2bf(v);
    short lo = f2bf(v - bf2f(hi));
    Bhi[t] = hi;
    Blo[t] = lo;
}

// ---------------------------------------------------------------------------
// MFMA GRU (round-4 structure: 7 waves/block, wave w owns column tile jt=w
// for all 3 gates; B frags register-resident). Round-5 changes:
//  - double-buffered h tables -> ONE barrier per step (was two)
//  - two-deep pipeline: tokens prefetched 2 steps ahead, wx gather issued a
//    full step before its epilogue use (round 4 covered only ~1/3 of the
//    L2-miss latency; occupancy is 1 block/CU so ILP is the only hiding)
// ---------------------------------------------------------------------------
__global__ __launch_bounds__(448, 2) void k_gru_mfma(
        const int* __restrict__ tok, const float* __restrict__ h0,
        const float* __restrict__ Wemb, const short* __restrict__ Bhi,
        const short* __restrict__ Blo, const float* __restrict__ b_hh,
        float* __restrict__ hout, int n_nodes) {
    __shared__ short hA[2][2][16 * 136];   // [buf][hi/lo][node*136+k]

    const int tid  = threadIdx.x;
    const int w    = tid >> 6;
    const int lane = tid & 63;
    const int n0   = lane & 15;
    const int q    = lane >> 4;
    const int node0 = blockIdx.x * 16;

    // ---- B fragments: 3 gates x 4 k-steps, hi+lo, loaded once ----
    bf16x8 bh[3][4], bl[3][4];
#pragma unroll
    for (int g = 0; g < 3; ++g)
#pragma unroll
        for (int ks = 0; ks < 4; ++ks) {
            long bo = ((long)((g * 7 + w) * 4 + ks) * 64 + lane) * 8;
            bh[g][ks] = *(const bf16x8*)&Bhi[bo];
            bl[g][ks] = *(const bf16x8*)&Blo[bo];
        }

    // ---- init h tables; buffer 1 zeroed so its k-pad (100..127) is 0 ----
    for (int i = tid; i < 16 * 128; i += 448) {
        int nd = i >> 7, c = i & 127;
        int row = node0 + nd; if (row >= n_nodes) row = n_nodes - 1;
        float v = (c < 100) ? h0[(long)row * 100 + c] : 0.f;
        short hi = f2bf(v);
        hA[0][0][nd * 136 + c] = hi;
        hA[0][1][nd * 136 + c] = f2bf(v - bf2f(hi));
        hA[1][0][nd * 136 + c] = 0;
        hA[1][1][nd * 136 + c] = 0;
    }

    const int j   = 16 * w + n0;
    const int jc  = j < 100 ? j : 99;
    const bool jok = (j < 100);
    const float bhr = b_hh[jc], bhz = b_hh[100 + jc], bhn = b_hh[200 + jc];

    int rows[4];
#pragma unroll
    for (int r = 0; r < 4; ++r) {
        int row = node0 + 4 * q + r;
        rows[r] = row < n_nodes ? row : n_nodes - 1;
    }
    float hprev[4];
#pragma unroll
    for (int r = 0; r < 4; ++r) hprev[r] = h0[(long)rows[r] * 100 + jc];

    __syncthreads();

    // ---- pipeline preload: tokens for steps 0 and 1, wx for step 0 ----
    int tb0[4], tb1[4];
#pragma unroll
    for (int r = 0; r < 4; ++r) tb0[r] = tok[(long)rows[r] * SEQL] * 300;
#pragma unroll
    for (int r = 0; r < 4; ++r) tb1[r] = tok[(long)rows[r] * SEQL + 1] * 300;
    float wxc[12];
#pragma unroll
    for (int g = 0; g < 3; ++g)
#pragma unroll
        for (int r = 0; r < 4; ++r) wxc[g * 4 + r] = Wemb[(long)tb0[r] + g * 100 + jc];

    int cur = 0;
#pragma unroll 1
    for (int l = 0; l < SEQL; ++l) {
        // issue next step's wx gather FIRST (full-step latency cover)
        float wxn[12];
        if (l < SEQL - 1) {
#pragma unroll
            for (int g = 0; g < 3; ++g)
#pragma unroll
                for (int r = 0; r < 4; ++r)
                    wxn[g * 4 + r] = Wemb[(long)tb1[r] + g * 100 + jc];
        }
        int tb2[4];
        if (l < SEQL - 2) {
#pragma unroll
            for (int r = 0; r < 4; ++r) tb2[r] = tok[(long)rows[r] * SEQL + l + 2] * 300;
        }

        // A-fragments from current buffer
        const short* hc0 = &hA[cur][0][0];
        const short* hc1 = &hA[cur][1][0];
        bf16x8 aHi[4], aLo[4];
#pragma unroll
        for (int ks = 0; ks < 4; ++ks) {
            int off = n0 * 136 + ks * 32 + q * 8;
            aHi[ks] = *(const bf16x8*)&hc0[off];
            aLo[ks] = *(const bf16x8*)&hc1[off];
        }

        f32x4 acc[3];
#pragma unroll
        for (int g = 0; g < 3; ++g) acc[g] = (f32x4){0.f, 0.f, 0.f, 0.f};
#pragma unroll
        for (int g = 0; g < 3; ++g)
#pragma unroll
            for (int ks = 0; ks < 4; ++ks) {
                acc[g] = __builtin_amdgcn_mfma_f32_16x16x32_bf16(aHi[ks], bh[g][ks], acc[g], 0, 0, 0);
                acc[g] = __builtin_amdgcn_mfma_f32_16x16x32_bf16(aHi[ks], bl[g][ks], acc[g], 0, 0, 0);
                acc[g] = __builtin_amdgcn_mfma_f32_16x16x32_bf16(aLo[ks], bh[g][ks], acc[g], 0, 0, 0);
            }

        // epilogue writes to the ALTERNATE buffer (no read/write hazard ->
        // single barrier per step)
        short* hn0 = &hA[cur ^ 1][0][0];
        short* hn1 = &hA[cur ^ 1][1][0];
#pragma unroll
        for (int r = 0; r < 4; ++r) {
            float pr = wxc[r]     + acc[0][r] + bhr;
            float pz = wxc[4 + r] + acc[1][r] + bhz;
            float rr = __builtin_amdgcn_rcpf(1.f + __expf(-pr));
            float zz = __builtin_amdgcn_rcpf(1.f + __expf(-pz));
            float pn = wxc[8 + r] + rr * (acc[2][r] + bhn);
            float th = 1.f - 2.f * __builtin_amdgcn_rcpf(1.f + __expf(2.f * pn));
            float hnew = (1.f - zz) * th + zz * hprev[r];
            hprev[r] = hnew;
            if (jok) {
                int off = (4 * q + r) * 136 + j;
                short hi = f2bf(hnew);
                hn0[off] = hi;
                hn1[off] = f2bf(hnew - bf2f(hi));
            }
        }
        if (l < SEQL - 1) {
#pragma unroll
            for (int i = 0; i < 12; ++i) wxc[i] = wxn[i];
#pragma unroll
            for (int r = 0; r < 4; ++r) tb1[r] = (l < SEQL - 2) ? tb2[r] : tb1[r];
        }
        __syncthreads();
        cur ^= 1;
    }

    for (int i = tid; i < 16 * 100; i += 448) {
        int nd = i / 100, c = i % 100;
        if (node0 + nd < n_nodes)
            hout[(long)(node0 + nd) * 100 + c] =
                bf2f(hA[cur][0][nd * 136 + c]) + bf2f(hA[cur][1][nd * 136 + c]);
    }
}

// ---------------------------------------------------------------------------
// Degree (int atomics)
// ---------------------------------------------------------------------------
__global__ void k_deg(const int* __restrict__ dst, int* __restrict__ degi, int E) {
    int e = blockIdx.x * blockDim.x + threadIdx.x;
    if (e < E) atomicAdd(&degi[dst[e]], 1);
}

// ---------------------------------------------------------------------------
// Single-block scan: row_start/cursor = exclusive prefix of degi; dinv fused.
// ---------------------------------------------------------------------------
__global__ __launch_bounds__(1024) void k_scan(const int* __restrict__ degi,
                                               int* __restrict__ rs, int* __restrict__ cursor,
                                               float* __restrict__ dinv, int N, int E) {
    __shared__ int part[1024];
    int tid = threadIdx.x;
    int chunk = (N + 1023) / 1024;
    int lo = tid * chunk, hi = lo + chunk;
    if (lo > N) lo = N;
    if (hi > N) hi = N;
    int s = 0;
    for (int i = lo; i < hi; ++i) s += degi[i];
    part[tid] = s;
    __syncthreads();
    for (int off = 1; off < 1024; off <<= 1) {
        int add = (tid >= off) ? part[tid - off] : 0;
        __syncthreads();
        part[tid] += add;
        __syncthreads();
    }
    int run = (tid > 0) ? part[tid - 1] : 0;
    for (int i = lo; i < hi; ++i) {
        rs[i] = run;
        cursor[i] = run;
        int d = degi[i];
        dinv[i] = rsqrtf((float)d + 1.0f);
        run += d;
    }
    if (tid == 0) rs[N] = E;
}

// ---------------------------------------------------------------------------
// Scatter edges into CSR order (by dst)
// ---------------------------------------------------------------------------
__global__ void k_scatter(const int* __restrict__ src, const int* __restrict__ dst,
                          int* __restrict__ cursor, int* __restrict__ esrc, int E) {
    int e = blockIdx.x * blockDim.x + threadIdx.x;
    if (e >= E) return;
    int pos = atomicAdd(&cursor[dst[e]], 1);
    esrc[pos] = src[e];
}

// ---------------------------------------------------------------------------
// xw[n, 4jq..] = x[n,:] @ W[:, 4jq..] — float4 output quads, b128 LDS reads.
// Each block handles 2048 quads (amortizes the W staging).
// ---------------------------------------------------------------------------
template <int K>
__global__ __launch_bounds__(256) void k_mm(const float* __restrict__ x,
                                            const float* __restrict__ W,
                                            float* __restrict__ out, int nquads) {
    __shared__ float sW[K * 100];
    for (int i = threadIdx.x; i < K * 100; i += 256) sW[i] = W[i];
    __syncthreads();
    int end = blockIdx.x * 2048 + 2048;
    if (end > nquads) end = nquads;
    for (int t = blockIdx.x * 2048 + threadIdx.x; t < end; t += 256) {
        int n = t / 25, jq = t % 25;
        const float4* xr = (const float4*)(x + (long)n * K);
        float4 acc = {0.f, 0.f, 0.f, 0.f};
#pragma unroll 4
        for (int d4 = 0; d4 < K / 4; ++d4) {
            float4 xv = xr[d4];
            float4 w0 = *(const float4*)&sW[(4 * d4 + 0) * 100 + 4 * jq];
            float4 w1 = *(const float4*)&sW[(4 * d4 + 1) * 100 + 4 * jq];
            float4 w2 = *(const float4*)&sW[(4 * d4 + 2) * 100 + 4 * jq];
            float4 w3 = *(const float4*)&sW[(4 * d4 + 3) * 100 + 4 * jq];
            acc.x = fmaf(xv.x, w0.x, fmaf(xv.y, w1.x, fmaf(xv.z, w2.x, fmaf(xv.w, w3.x, acc.x))));
            acc.y = fmaf(xv.x, w0.y, fmaf(xv.y, w1.y, fmaf(xv.z, w2.y, fmaf(xv.w, w3.y, acc.y))));
            acc.z = fmaf(xv.x, w0.z, fmaf(xv.y, w1.z, fmaf(xv.z, w2.z, fmaf(xv.w, w3.z, acc.z))));
            acc.w = fmaf(xv.x, w0.w, fmaf(xv.y, w1.w, fmaf(xv.z, w2.w, fmaf(xv.w, w3.w, acc.w))));
        }
        ((float4*)out)[t] = acc;
    }
}

// ---------------------------------------------------------------------------
// Conv1 finish: CSR gather (no atomics) + self term + bias, then
// xc1 = v ; xbig = relu([v, hn[idx]]).  Thread per (n, jq).
// ---------------------------------------------------------------------------
__global__ void k_conv1_fin(const int* __restrict__ rs, const int* __restrict__ esrc,
                            const float* __restrict__ xw, const float* __restrict__ dinv,
                            const float* __restrict__ b1, const float* __restrict__ hn,
                            const int* __restrict__ idx, float* __restrict__ xc1,
                            float* __restrict__ xbig, int N) {
    int t = blockIdx.x * blockDim.x + threadIdx.x;
    if (t >= N * 25) return;
    int n = t / 25, jq = t % 25;
    float dn = dinv[n];
    float4 acc = {0.f, 0.f, 0.f, 0.f};
    int e1 = rs[n + 1];
    for (int e = rs[n]; e < e1; ++e) {
        int s = esrc[e];
        float ds = dinv[s];
        float4 xs = ((const float4*)xw)[s * 25 + jq];
        acc.x = fmaf(xs.x, ds, acc.x);
        acc.y = fmaf(xs.y, ds, acc.y);
        acc.z = fmaf(xs.z, ds, acc.z);
        acc.w = fmaf(xs.w, ds, acc.w);
    }
    float4 xs = ((const float4*)xw)[t];
    float4 bq = ((const float4*)b1)[jq];
    float dn2 = dn * dn;
    float4 v;
    v.x = fmaf(acc.x, dn, fmaf(xs.x, dn2, bq.x));
    v.y = fmaf(acc.y, dn, fmaf(xs.y, dn2, bq.y));
    v.z = fmaf(acc.z, dn, fmaf(xs.z, dn2, bq.z));
    v.w = fmaf(acc.w, dn, fmaf(xs.w, dn2, bq.w));
    ((float4*)xc1)[t] = v;
    float4 rv = ((const float4*)hn)[(long)idx[n] * 25 + jq];
    float4 a = {fmaxf(v.x, 0.f), fmaxf(v.y, 0.f), fmaxf(v.z, 0.f), fmaxf(v.w, 0.f)};
    float4 b = {fmaxf(rv.x, 0.f), fmaxf(rv.y, 0.f), fmaxf(rv.z, 0.f), fmaxf(rv.w, 0.f)};
    ((float4*)xbig)[n * 50 + jq] = a;
    ((float4*)xbig)[n * 50 + 25 + jq] = b;
}

// ---------------------------------------------------------------------------
// Conv2 finish: out = [relu(agg2 + self + b2), xc1[idx]]
// ---------------------------------------------------------------------------
__global__ void k_conv2_fin(const int* __restrict__ rs, const int* __restrict__ esrc,
                            const float* __restrict__ xw, const float* __restrict__ dinv,
                            const float* __restrict__ b2, const float* __restrict__ xc1,
                            const int* __restrict__ idx, float* __restrict__ out, int N) {
    int t = blockIdx.x * blockDim.x + threadIdx.x;
    if (t >= N * 25) return;
    int n = t / 25, jq = t % 25;
    float dn = dinv[n];
    float4 acc = {0.f, 0.f, 0.f, 0.f};
    int e1 = rs[n + 1];
    for (int e = rs[n]; e < e1; ++e) {
        int s = esrc[e];
        float ds = dinv[s];
        float4 xs = ((const float4*)xw)[s * 25 + jq];
        acc.x = fmaf(xs.x, ds, acc.x);
        acc.y = fmaf(xs.y, ds, acc.y);
        acc.z = fmaf(xs.z, ds, acc.z);
        acc.w = fmaf(xs.w, ds, acc.w);
    }
    float4 xs = ((const float4*)xw)[t];
    float4 bq = ((const float4*)b2)[jq];
    float dn2 = dn * dn;
    float4 v;
    v.x = fmaxf(fmaf(acc.x, dn, fmaf(xs.x, dn2, bq.x)), 0.f);
    v.y = fmaxf(fmaf(acc.y, dn, fmaf(xs.y, dn2, bq.y)), 0.f);
    v.z = fmaxf(fmaf(acc.z, dn, fmaf(xs.z, dn2, bq.z)), 0.f);
    v.w = fmaxf(fmaf(acc.w, dn, fmaf(xs.w, dn2, bq.w)), 0.f);
    float4 rv = ((const float4*)xc1)[(long)idx[n] * 25 + jq];
    ((float4*)out)[n * 50 + jq] = v;
    ((float4*)out)[n * 50 + 25 + jq] = rv;
}

// ---------------------------------------------------------------------------
extern "C" void kernel_launch(void* const* d_in, const int* in_sizes, int n_in,
                              void* d_out, int out_size, void* d_ws, size_t ws_size,
                              hipStream_t stream) {
    const int*   feat    = (const int*)d_in[0];
    const int*   edges   = (const int*)d_in[1];
    const int*   indices = (const int*)d_in[2];
    const float* h0      = (const float*)d_in[3];
    const float* emb     = (const float*)d_in[4];
    const float* W_ih    = (const float*)d_in[5];
    const float* W_hh    = (const float*)d_in[6];
    const float* b_ih    = (const float*)d_in[7];
    const float* b_hh    = (const float*)d_in[8];
    const float* W1      = (const float*)d_in[9];
    const float* b1      = (const float*)d_in[10];
    const float* W2      = (const float*)d_in[11];
    const float* b2      = (const float*)d_in[12];
    float* out = (float*)d_out;

    const int N = in_sizes[2];
    const int E = in_sizes[1] / 2;
    const int V = in_sizes[4] / D_IN;
    const int* src = edges;
    const int* dst = edges + E;

    float* ws   = (float*)d_ws;
    float* hbuf = ws;                         // N*100
    float* Wemb = hbuf + (long)N * H;         // V*300 (reused as xw after GRU)
    float* xw   = Wemb;                       // reuse: N*100
    float* xc1  = Wemb + (long)V * 300;       // N*100
    float* xbig = xc1 + (long)N * 100;        // N*200
    float* dinv = xbig + (long)N * 200;       // N
    short* Bhi  = (short*)(dinv + N);         // 43008 bf16
    short* Blo  = Bhi + 43008;                // 43008 bf16
    int*   degi = (int*)(Blo + 43008);        // N
    int*   rs   = degi + N;                   // N+1
    int*   cursor = rs + N + 1;               // N
    int*   esrc = cursor + N;                 // E
    (void)ws_size; (void)n_in; (void)out_size;

    const int B = 256;

    hipMemsetAsync(degi, 0, (size_t)N * sizeof(int), stream);
    k_deg<<<(E + B - 1) / B, B, 0, stream>>>(dst, degi, E);
    k_scan<<<1, 1024, 0, stream>>>(degi, rs, cursor, dinv, N, E);
    k_scatter<<<(E + B - 1) / B, B, 0, stream>>>(src, dst, cursor, esrc, E);

    k_bpack<<<(43008 + B - 1) / B, B, 0, stream>>>(W_hh, Bhi, Blo, 43008);
    k_wemb_t<<<(V + 63) / 64, 512, 0, stream>>>(emb, W_ih, b_ih, Wemb, V);

    k_gru_mfma<<<(N + 15) / 16, 448, 0, stream>>>(feat, h0, Wemb, Bhi, Blo, b_hh, hbuf, N);

    {
        int nquads = N * 25;
        k_mm<100><<<(nquads + 2047) / 2048, 256, 0, stream>>>(hbuf, W1, xw, nquads);
        k_conv1_fin<<<(nquads + B - 1) / B, B, 0, stream>>>(rs, esrc, xw, dinv, b1, hbuf,
                                                            indices, xc1, xbig, N);
        k_mm<200><<<(nquads + 2047) / 2048, 256, 0, stream>>>(xbig, W2, xw, nquads);
        k_conv2_fin<<<(nquads + B - 1) / B, B, 0, stream>>>(rs, esrc, xw, dinv, b2, xc1,
                                                            indices, out, N);
    }
}